// Round 1
// baseline (2287.974 us; speedup 1.0000x reference)
//
#include <hip/hip_runtime.h>
#include <math.h>

#define NN 20000
#define NE 160000
#define NG 1000
#define IND 11
#define H 128
#define ED 3
#define NL 5
#define ZD (2*H+ED)   /* 259 */
#define ZS (ZD+1)     /* 260, float4-aligned stride */
#define EB 16         /* edges per block */
#define BN_EPSF 1e-5f

__global__ void deg_kernel(const int* __restrict__ dst, float* __restrict__ degf) {
    int e = blockIdx.x * blockDim.x + threadIdx.x;
    if (e < NE) atomicAdd(&degf[dst[e]], 1.0f);
}

__global__ __launch_bounds__(H) void hin_kernel(const float* __restrict__ x,
                                                const float* __restrict__ Win,
                                                const float* __restrict__ bin,
                                                float* __restrict__ h) {
    int n = blockIdx.x;
    int j = threadIdx.x;
    __shared__ float xr[IND];
    if (j < IND) xr[j] = x[n * IND + j];
    __syncthreads();
    float acc = bin[j];
#pragma unroll
    for (int k = 0; k < IND; ++k) acc = fmaf(xr[k], Win[k * H + j], acc);
    h[n * H + j] = acc;
}

__global__ __launch_bounds__(H) void edge_kernel(const float* __restrict__ h,
                                                 const int* __restrict__ src,
                                                 const int* __restrict__ dst,
                                                 const float* __restrict__ ea,
                                                 const float* __restrict__ Wf,
                                                 const float* __restrict__ bf,
                                                 const float* __restrict__ Ws,
                                                 const float* __restrict__ bs,
                                                 float* __restrict__ agg) {
    __shared__ __align__(16) float z[EB][ZS];
    __shared__ int sd[EB];
    int j = threadIdx.x;
    int e0 = blockIdx.x * EB;
    // stage z = [h[dst], h[src], edge_attr] for EB edges
    for (int e = 0; e < EB; ++e) {
        int de = dst[e0 + e];
        int se = src[e0 + e];
        z[e][j]     = h[de * H + j];
        z[e][H + j] = h[se * H + j];
        if (j < ED) z[e][2 * H + j] = ea[(e0 + e) * ED + j];
        if (j == 0) sd[e] = de;
    }
    __syncthreads();

    float accF[EB], accS[EB];
#pragma unroll
    for (int e = 0; e < EB; ++e) { accF[e] = bf[j]; accS[e] = bs[j]; }

    for (int k = 0; k < 2 * H; k += 4) {
        float wf0 = Wf[(k + 0) * H + j];
        float wf1 = Wf[(k + 1) * H + j];
        float wf2 = Wf[(k + 2) * H + j];
        float wf3 = Wf[(k + 3) * H + j];
        float ws0 = Ws[(k + 0) * H + j];
        float ws1 = Ws[(k + 1) * H + j];
        float ws2 = Ws[(k + 2) * H + j];
        float ws3 = Ws[(k + 3) * H + j];
#pragma unroll
        for (int e = 0; e < EB; ++e) {
            float4 z4 = *(const float4*)&z[e][k];
            accF[e] = fmaf(z4.x, wf0, fmaf(z4.y, wf1, fmaf(z4.z, wf2, fmaf(z4.w, wf3, accF[e]))));
            accS[e] = fmaf(z4.x, ws0, fmaf(z4.y, ws1, fmaf(z4.z, ws2, fmaf(z4.w, ws3, accS[e]))));
        }
    }
    // tail k = 256..258 (edge_attr columns)
    {
        float wfa = Wf[256 * H + j], wfb = Wf[257 * H + j], wfc = Wf[258 * H + j];
        float wsa = Ws[256 * H + j], wsb = Ws[257 * H + j], wsc = Ws[258 * H + j];
#pragma unroll
        for (int e = 0; e < EB; ++e) {
            float za = z[e][256], zb = z[e][257], zc = z[e][258];
            accF[e] = fmaf(za, wfa, fmaf(zb, wfb, fmaf(zc, wfc, accF[e])));
            accS[e] = fmaf(za, wsa, fmaf(zb, wsb, fmaf(zc, wsc, accS[e])));
        }
    }
#pragma unroll
    for (int e = 0; e < EB; ++e) {
        float f = accF[e], s = accS[e];
        float sig = 1.0f / (1.0f + expf(-f));
        float sp  = fmaxf(s, 0.0f) + log1pf(expf(-fabsf(s)));
        atomicAdd(&agg[sd[e] * H + j], sig * sp);
    }
}

__global__ __launch_bounds__(H) void resid_sum_kernel(float* __restrict__ h,
                                                      const float* __restrict__ agg,
                                                      const float* __restrict__ degf,
                                                      float* __restrict__ sum) {
    int j = threadIdx.x;
    float ls = 0.0f;
    for (int n = blockIdx.x; n < NN; n += gridDim.x) {
        float d = degf[n];
        d = d < 1.0f ? 1.0f : d;
        float v = h[n * H + j] + agg[n * H + j] / d;
        h[n * H + j] = v;
        ls += v;
    }
    atomicAdd(&sum[j], ls);
}

__global__ __launch_bounds__(H) void sumsq_kernel(const float* __restrict__ h,
                                                  const float* __restrict__ sum,
                                                  float* __restrict__ sumsq) {
    int j = threadIdx.x;
    float mu = sum[j] * (1.0f / NN);
    float ls = 0.0f;
    for (int n = blockIdx.x; n < NN; n += gridDim.x) {
        float d = h[n * H + j] - mu;
        ls = fmaf(d, d, ls);
    }
    atomicAdd(&sumsq[j], ls);
}

__global__ __launch_bounds__(H) void bn_kernel(float* __restrict__ h,
                                               const float* __restrict__ sum,
                                               const float* __restrict__ sumsq,
                                               const float* __restrict__ gamma,
                                               const float* __restrict__ beta) {
    int j = threadIdx.x;
    float mu  = sum[j] * (1.0f / NN);
    float var = sumsq[j] * (1.0f / NN);
    float sc  = gamma[j] / sqrtf(var + BN_EPSF);
    float sh  = beta[j] - mu * sc;
    for (int n = blockIdx.x; n < NN; n += gridDim.x) {
        float v = fmaf(h[n * H + j], sc, sh);
        h[n * H + j] = v > 0.0f ? v : 0.0f;
    }
}

__global__ __launch_bounds__(H) void pool_kernel(const float* __restrict__ h,
                                                 const int* __restrict__ batch,
                                                 float* __restrict__ g,
                                                 float* __restrict__ cnt) {
    int j = threadIdx.x;
    for (int n = blockIdx.x; n < NN; n += gridDim.x) {
        int b = batch[n];
        atomicAdd(&g[b * H + j], h[n * H + j]);
        if (j == 0) atomicAdd(&cnt[b], 1.0f);
    }
}

__global__ __launch_bounds__(H) void mlp_kernel(const float* __restrict__ g,
                                                const float* __restrict__ cnt,
                                                const float* __restrict__ W1,
                                                const float* __restrict__ b1,
                                                const float* __restrict__ W2,
                                                const float* __restrict__ b2,
                                                const float* __restrict__ W3,
                                                const float* __restrict__ b3,
                                                float* __restrict__ out) {
    int gid = blockIdx.x, j = threadIdx.x;
    __shared__ float s1[H];
    __shared__ float s2[H];
    __shared__ float wsum[2];
    float c = cnt[gid];
    c = c < 1.0f ? 1.0f : c;
    s1[j] = g[gid * H + j] / c;
    __syncthreads();
    float a = b1[j];
    for (int k = 0; k < H; ++k) a = fmaf(s1[k], W1[k * H + j], a);
    a = a > 0.0f ? a : 0.0f;
    s2[j] = a;
    __syncthreads();
    float t = b2[j];
    for (int k = 0; k < H; ++k) t = fmaf(s2[k], W2[k * H + j], t);
    t = t > 0.0f ? t : 0.0f;
    float p = t * W3[j];
    for (int off = 32; off > 0; off >>= 1) p += __shfl_down(p, off, 64);
    if ((j & 63) == 0) wsum[j >> 6] = p;
    __syncthreads();
    if (j == 0) out[gid] = wsum[0] + wsum[1] + b3[0];
}

extern "C" void kernel_launch(void* const* d_in, const int* in_sizes, int n_in,
                              void* d_out, int out_size, void* d_ws, size_t ws_size,
                              hipStream_t stream) {
    const float* x     = (const float*)d_in[0];
    const int*   ei    = (const int*)d_in[1];
    const int*   srcp  = ei;        // edge_index[0] = source
    const int*   dstp  = ei + NE;   // edge_index[1] = target (aggregation index)
    const int*   batch = (const int*)d_in[2];
    const float* ea    = (const float*)d_in[3];
    const float* Win   = (const float*)d_in[4];
    const float* bin   = (const float*)d_in[5];
    const float* Wf    = (const float*)d_in[6];
    const float* bf    = (const float*)d_in[7];
    const float* Ws    = (const float*)d_in[8];
    const float* bs    = (const float*)d_in[9];
    const float* gamma = (const float*)d_in[10];
    const float* beta  = (const float*)d_in[11];
    const float* W1    = (const float*)d_in[12];
    const float* b1    = (const float*)d_in[13];
    const float* W2    = (const float*)d_in[14];
    const float* b2    = (const float*)d_in[15];
    const float* W3    = (const float*)d_in[16];
    const float* b3    = (const float*)d_in[17];
    float* out = (float*)d_out;

    float* ws    = (float*)d_ws;
    float* h     = ws;                 // NN*H
    float* agg   = h + (size_t)NN * H; // NN*H
    float* sum   = agg + (size_t)NN * H; // H
    float* sumsq = sum + H;            // H
    float* degf  = sumsq + H;          // NN
    float* g     = degf + NN;          // NG*H
    float* cnt   = g + (size_t)NG * H; // NG

    hipMemsetAsync(degf, 0, NN * sizeof(float), stream);
    deg_kernel<<<(NE + 255) / 256, 256, 0, stream>>>(dstp, degf);
    hin_kernel<<<NN, H, 0, stream>>>(x, Win, bin, h);

    for (int l = 0; l < NL; ++l) {
        hipMemsetAsync(agg, 0, ((size_t)NN * H + 2 * H) * sizeof(float), stream);
        edge_kernel<<<NE / EB, H, 0, stream>>>(h, srcp, dstp, ea,
                                               Wf + (size_t)l * ZD * H, bf + (size_t)l * H,
                                               Ws + (size_t)l * ZD * H, bs + (size_t)l * H,
                                               agg);
        resid_sum_kernel<<<256, H, 0, stream>>>(h, agg, degf, sum);
        sumsq_kernel<<<256, H, 0, stream>>>(h, sum, sumsq);
        bn_kernel<<<256, H, 0, stream>>>(h, sum, sumsq, gamma + (size_t)l * H, beta + (size_t)l * H);
    }

    hipMemsetAsync(g, 0, ((size_t)NG * H + NG) * sizeof(float), stream);
    pool_kernel<<<2048, H, 0, stream>>>(h, batch, g, cnt);
    mlp_kernel<<<NG, H, 0, stream>>>(g, cnt, W1, b1, W2, b2, W3, b3, out);
}

// Round 2
// 1504.631 us; speedup vs baseline: 1.5206x; 1.5206x over previous
//
#include <hip/hip_runtime.h>
#include <math.h>

#define NN 20000
#define NE 160000
#define NG 1000
#define IND 11
#define H 128
#define ED 3
#define NL 5
#define NB 16          /* nodes per block in node_gemm */
#define BN_EPSF 1e-5f

__global__ void deg_kernel(const int* __restrict__ dst, float* __restrict__ degf) {
    int e = blockIdx.x * blockDim.x + threadIdx.x;
    if (e < NE) atomicAdd(&degf[dst[e]], 1.0f);
}

__global__ __launch_bounds__(H) void hin_kernel(const float* __restrict__ x,
                                                const float* __restrict__ Win,
                                                const float* __restrict__ bin,
                                                float* __restrict__ h) {
    int n = blockIdx.x;
    int j = threadIdx.x;
    __shared__ float xr[IND];
    if (j < IND) xr[j] = x[n * IND + j];
    __syncthreads();
    float acc = bin[j];
#pragma unroll
    for (int k = 0; k < IND; ++k) acc = fmaf(xr[k], Win[k * H + j], acc);
    h[n * H + j] = acc;
}

// Computes P = h @ W[0:128] and Q = h @ W[128:256] for one weight matrix W
// (blockIdx.y=0 -> Wf -> Pf,Qf ; blockIdx.y=1 -> Ws -> Ps,Qs).
// Block = 128 threads (j = column). NB node rows staged in LDS (broadcast reads).
__global__ __launch_bounds__(H) void node_gemm_kernel(const float* __restrict__ h,
                                                      const float* __restrict__ Wf,
                                                      const float* __restrict__ Ws,
                                                      float* __restrict__ Pf,
                                                      float* __restrict__ Qf,
                                                      float* __restrict__ Ps,
                                                      float* __restrict__ Qs) {
    __shared__ __align__(16) float za[NB][H];
    int j = threadIdx.x;
    int n0 = blockIdx.x * NB;
    const float* W = blockIdx.y ? Ws : Wf;
    float* P = blockIdx.y ? Ps : Pf;
    float* Q = blockIdx.y ? Qs : Qf;

#pragma unroll
    for (int n = 0; n < NB; ++n) za[n][j] = h[(size_t)(n0 + n) * H + j];
    __syncthreads();

    float accP[NB], accQ[NB];
#pragma unroll
    for (int n = 0; n < NB; ++n) { accP[n] = 0.0f; accQ[n] = 0.0f; }

    for (int k = 0; k < H; k += 4) {
        float p0 = W[(k + 0) * H + j];
        float p1 = W[(k + 1) * H + j];
        float p2 = W[(k + 2) * H + j];
        float p3 = W[(k + 3) * H + j];
        float q0 = W[(H + k + 0) * H + j];
        float q1 = W[(H + k + 1) * H + j];
        float q2 = W[(H + k + 2) * H + j];
        float q3 = W[(H + k + 3) * H + j];
#pragma unroll
        for (int n = 0; n < NB; ++n) {
            float4 z4 = *(const float4*)&za[n][k];
            accP[n] = fmaf(z4.x, p0, fmaf(z4.y, p1, fmaf(z4.z, p2, fmaf(z4.w, p3, accP[n]))));
            accQ[n] = fmaf(z4.x, q0, fmaf(z4.y, q1, fmaf(z4.z, q2, fmaf(z4.w, q3, accQ[n]))));
        }
    }
#pragma unroll
    for (int n = 0; n < NB; ++n) {
        P[(size_t)(n0 + n) * H + j] = accP[n];
        Q[(size_t)(n0 + n) * H + j] = accQ[n];
    }
}

// Per edge: msgF = Pf[dst]+Qf[src]+ea.Wf[256:259]+bf ; msgS likewise;
// agg[dst] += sigmoid(msgF)*softplus(msgS).  2 edges per 256-thread block iter.
__global__ __launch_bounds__(256) void edge_gather_kernel(const int* __restrict__ src,
                                                          const int* __restrict__ dst,
                                                          const float* __restrict__ ea,
                                                          const float* __restrict__ Wf,
                                                          const float* __restrict__ bf,
                                                          const float* __restrict__ Ws,
                                                          const float* __restrict__ bs,
                                                          const float* __restrict__ Pf,
                                                          const float* __restrict__ Qf,
                                                          const float* __restrict__ Ps,
                                                          const float* __restrict__ Qs,
                                                          float* __restrict__ agg) {
    int j = threadIdx.x & (H - 1);
    int half = threadIdx.x >> 7;
    // hoist edge-attr weight columns + biases (same for every edge)
    float wf0 = Wf[256 * H + j], wf1 = Wf[257 * H + j], wf2 = Wf[258 * H + j];
    float ws0 = Ws[256 * H + j], ws1 = Ws[257 * H + j], ws2 = Ws[258 * H + j];
    float bfj = bf[j], bsj = bs[j];

    for (int e = blockIdx.x * 2 + half; e < NE; e += gridDim.x * 2) {
        int d = dst[e];
        int s = src[e];
        float e0 = ea[e * ED + 0], e1 = ea[e * ED + 1], e2 = ea[e * ED + 2];
        float f = Pf[(size_t)d * H + j] + Qf[(size_t)s * H + j];
        float v = Ps[(size_t)d * H + j] + Qs[(size_t)s * H + j];
        f = fmaf(e0, wf0, fmaf(e1, wf1, fmaf(e2, wf2, f + bfj)));
        v = fmaf(e0, ws0, fmaf(e1, ws1, fmaf(e2, ws2, v + bsj)));
        float sig = 1.0f / (1.0f + expf(-f));
        float sp  = fmaxf(v, 0.0f) + log1pf(expf(-fabsf(v)));
        atomicAdd(&agg[(size_t)d * H + j], sig * sp);
    }
}

__global__ __launch_bounds__(H) void resid_sum_kernel(float* __restrict__ h,
                                                      const float* __restrict__ agg,
                                                      const float* __restrict__ degf,
                                                      float* __restrict__ sum) {
    int j = threadIdx.x;
    float ls = 0.0f;
    for (int n = blockIdx.x; n < NN; n += gridDim.x) {
        float d = degf[n];
        d = d < 1.0f ? 1.0f : d;
        float v = h[n * H + j] + agg[n * H + j] / d;
        h[n * H + j] = v;
        ls += v;
    }
    atomicAdd(&sum[j], ls);
}

__global__ __launch_bounds__(H) void sumsq_kernel(const float* __restrict__ h,
                                                  const float* __restrict__ sum,
                                                  float* __restrict__ sumsq) {
    int j = threadIdx.x;
    float mu = sum[j] * (1.0f / NN);
    float ls = 0.0f;
    for (int n = blockIdx.x; n < NN; n += gridDim.x) {
        float d = h[n * H + j] - mu;
        ls = fmaf(d, d, ls);
    }
    atomicAdd(&sumsq[j], ls);
}

__global__ __launch_bounds__(H) void bn_kernel(float* __restrict__ h,
                                               const float* __restrict__ sum,
                                               const float* __restrict__ sumsq,
                                               const float* __restrict__ gamma,
                                               const float* __restrict__ beta) {
    int j = threadIdx.x;
    float mu  = sum[j] * (1.0f / NN);
    float var = sumsq[j] * (1.0f / NN);
    float sc  = gamma[j] / sqrtf(var + BN_EPSF);
    float sh  = beta[j] - mu * sc;
    for (int n = blockIdx.x; n < NN; n += gridDim.x) {
        float v = fmaf(h[n * H + j], sc, sh);
        h[n * H + j] = v > 0.0f ? v : 0.0f;
    }
}

__global__ __launch_bounds__(H) void pool_kernel(const float* __restrict__ h,
                                                 const int* __restrict__ batch,
                                                 float* __restrict__ g,
                                                 float* __restrict__ cnt) {
    int j = threadIdx.x;
    for (int n = blockIdx.x; n < NN; n += gridDim.x) {
        int b = batch[n];
        atomicAdd(&g[b * H + j], h[n * H + j]);
        if (j == 0) atomicAdd(&cnt[b], 1.0f);
    }
}

__global__ __launch_bounds__(H) void mlp_kernel(const float* __restrict__ g,
                                                const float* __restrict__ cnt,
                                                const float* __restrict__ W1,
                                                const float* __restrict__ b1,
                                                const float* __restrict__ W2,
                                                const float* __restrict__ b2,
                                                const float* __restrict__ W3,
                                                const float* __restrict__ b3,
                                                float* __restrict__ out) {
    int gid = blockIdx.x, j = threadIdx.x;
    __shared__ float s1[H];
    __shared__ float s2[H];
    __shared__ float wsum[2];
    float c = cnt[gid];
    c = c < 1.0f ? 1.0f : c;
    s1[j] = g[gid * H + j] / c;
    __syncthreads();
    float a = b1[j];
    for (int k = 0; k < H; ++k) a = fmaf(s1[k], W1[k * H + j], a);
    a = a > 0.0f ? a : 0.0f;
    s2[j] = a;
    __syncthreads();
    float t = b2[j];
    for (int k = 0; k < H; ++k) t = fmaf(s2[k], W2[k * H + j], t);
    t = t > 0.0f ? t : 0.0f;
    float p = t * W3[j];
    for (int off = 32; off > 0; off >>= 1) p += __shfl_down(p, off, 64);
    if ((j & 63) == 0) wsum[j >> 6] = p;
    __syncthreads();
    if (j == 0) out[gid] = wsum[0] + wsum[1] + b3[0];
}

extern "C" void kernel_launch(void* const* d_in, const int* in_sizes, int n_in,
                              void* d_out, int out_size, void* d_ws, size_t ws_size,
                              hipStream_t stream) {
    const float* x     = (const float*)d_in[0];
    const int*   ei    = (const int*)d_in[1];
    const int*   srcp  = ei;        // edge_index[0] = source (x_j)
    const int*   dstp  = ei + NE;   // edge_index[1] = target (aggregation index)
    const int*   batch = (const int*)d_in[2];
    const float* ea    = (const float*)d_in[3];
    const float* Win   = (const float*)d_in[4];
    const float* bin   = (const float*)d_in[5];
    const float* Wf    = (const float*)d_in[6];
    const float* bf    = (const float*)d_in[7];
    const float* Ws    = (const float*)d_in[8];
    const float* bs    = (const float*)d_in[9];
    const float* gamma = (const float*)d_in[10];
    const float* beta  = (const float*)d_in[11];
    const float* W1    = (const float*)d_in[12];
    const float* b1    = (const float*)d_in[13];
    const float* W2    = (const float*)d_in[14];
    const float* b2    = (const float*)d_in[15];
    const float* W3    = (const float*)d_in[16];
    const float* b3    = (const float*)d_in[17];
    float* out = (float*)d_out;

    const size_t NH = (size_t)NN * H;
    float* ws    = (float*)d_ws;
    float* h     = ws;               // NN*H
    float* agg   = h + NH;           // NN*H
    float* sum   = agg + NH;         // H
    float* sumsq = sum + H;          // H
    float* degf  = sumsq + H;        // NN
    float* g     = degf + NN;        // NG*H
    float* cnt   = g + (size_t)NG * H; // NG
    float* Pf    = cnt + NG;         // NN*H
    float* Qf    = Pf + NH;          // NN*H
    float* Ps    = Qf + NH;          // NN*H
    float* Qs    = Ps + NH;          // NN*H

    hipMemsetAsync(degf, 0, NN * sizeof(float), stream);
    deg_kernel<<<(NE + 255) / 256, 256, 0, stream>>>(dstp, degf);
    hin_kernel<<<NN, H, 0, stream>>>(x, Win, bin, h);

    const size_t ZDH = (size_t)(2 * H + ED) * H;   // 259*128 stride per layer
    for (int l = 0; l < NL; ++l) {
        const float* Wfl = Wf + (size_t)l * ZDH;
        const float* Wsl = Ws + (size_t)l * ZDH;
        node_gemm_kernel<<<dim3(NN / NB, 2), H, 0, stream>>>(h, Wfl, Wsl, Pf, Qf, Ps, Qs);
        hipMemsetAsync(agg, 0, (NH + 2 * H) * sizeof(float), stream);  // agg + sum + sumsq
        edge_gather_kernel<<<2000, 256, 0, stream>>>(srcp, dstp, ea,
                                                     Wfl, bf + (size_t)l * H,
                                                     Wsl, bs + (size_t)l * H,
                                                     Pf, Qf, Ps, Qs, agg);
        resid_sum_kernel<<<256, H, 0, stream>>>(h, agg, degf, sum);
        sumsq_kernel<<<256, H, 0, stream>>>(h, sum, sumsq);
        bn_kernel<<<256, H, 0, stream>>>(h, sum, sumsq, gamma + (size_t)l * H, beta + (size_t)l * H);
    }

    hipMemsetAsync(g, 0, ((size_t)NG * H + NG) * sizeof(float), stream);
    pool_kernel<<<2048, H, 0, stream>>>(h, batch, g, cnt);
    mlp_kernel<<<NG, H, 0, stream>>>(g, cnt, W1, b1, W2, b2, W3, b3, out);
}

// Round 3
// 1039.920 us; speedup vs baseline: 2.2001x; 1.4469x over previous
//
#include <hip/hip_runtime.h>
#include <math.h>

#define NN 20000
#define NE 160000
#define NG 1000
#define IND 11
#define H 128
#define ED 3
#define NL 5
#define NB 16          /* nodes per block in node_gemm */
#define BN_EPSF 1e-5f

__global__ void deg_kernel(const int* __restrict__ dst, float* __restrict__ degf) {
    int e = blockIdx.x * blockDim.x + threadIdx.x;
    if (e < NE) atomicAdd(&degf[dst[e]], 1.0f);
}

__global__ void invdeg_kernel(float* __restrict__ degf) {
    int n = blockIdx.x * blockDim.x + threadIdx.x;
    if (n < NN) {
        float d = degf[n];
        degf[n] = d < 1.0f ? 1.0f : 1.0f / d;
    }
}

__global__ __launch_bounds__(H) void hin_kernel(const float* __restrict__ x,
                                                const float* __restrict__ Win,
                                                const float* __restrict__ bin,
                                                float* __restrict__ h) {
    int n = blockIdx.x;
    int j = threadIdx.x;
    __shared__ float xr[IND];
    if (j < IND) xr[j] = x[n * IND + j];
    __syncthreads();
    float acc = bin[j];
#pragma unroll
    for (int k = 0; k < IND; ++k) acc = fmaf(xr[k], Win[k * H + j], acc);
    h[n * H + j] = acc;
}

// One block: stages NB rows of h (optionally applying previous layer's BN+ReLU,
// writing the normalized h back), then computes all four node tables:
//   Pf = h@Wf[0:H], Qf = h@Wf[H:2H], Ps = h@Ws[0:H], Qs = h@Ws[H:2H].
// 16 FMAs per ds_read_b128; weights software-pipelined one k-group ahead.
__global__ __launch_bounds__(H) void node_gemm_kernel(float* __restrict__ h,
                                                      const float* __restrict__ Wf,
                                                      const float* __restrict__ Ws,
                                                      const float* __restrict__ sum,
                                                      const float* __restrict__ sumsq,
                                                      const float* __restrict__ gamma,
                                                      const float* __restrict__ beta,
                                                      int applyBN,
                                                      float* __restrict__ Pf,
                                                      float* __restrict__ Qf,
                                                      float* __restrict__ Ps,
                                                      float* __restrict__ Qs) {
    __shared__ __align__(16) float za[NB][H];
    int j = threadIdx.x;
    int n0 = blockIdx.x * NB;

    if (applyBN) {
        float mu  = sum[j] * (1.0f / NN);
        float var = sumsq[j] * (1.0f / NN) - mu * mu;
        float sc  = gamma[j] * rsqrtf(var + BN_EPSF);
        float sh  = beta[j] - mu * sc;
#pragma unroll
        for (int n = 0; n < NB; ++n) {
            float v = fmaf(h[(size_t)(n0 + n) * H + j], sc, sh);
            v = v > 0.0f ? v : 0.0f;
            h[(size_t)(n0 + n) * H + j] = v;
            za[n][j] = v;
        }
    } else {
#pragma unroll
        for (int n = 0; n < NB; ++n) za[n][j] = h[(size_t)(n0 + n) * H + j];
    }
    __syncthreads();

    float aPf[NB], aQf[NB], aPs[NB], aQs[NB];
#pragma unroll
    for (int n = 0; n < NB; ++n) { aPf[n] = 0.f; aQf[n] = 0.f; aPs[n] = 0.f; aQs[n] = 0.f; }

    const float* wfP = Wf + j;          // Wf[k][j]      = wfP[k*H]
    const float* wfQ = Wf + H * H + j;  // Wf[H+k][j]
    const float* wsP = Ws + j;
    const float* wsQ = Ws + H * H + j;

    float cur[16], nxt[16];
#pragma unroll
    for (int t = 0; t < 4; ++t) {
        cur[t]      = wfP[t * H];
        cur[4 + t]  = wfQ[t * H];
        cur[8 + t]  = wsP[t * H];
        cur[12 + t] = wsQ[t * H];
    }

    for (int k = 0; k < H; k += 4) {
        if (k + 4 < H) {
#pragma unroll
            for (int t = 0; t < 4; ++t) {
                nxt[t]      = wfP[(k + 4 + t) * H];
                nxt[4 + t]  = wfQ[(k + 4 + t) * H];
                nxt[8 + t]  = wsP[(k + 4 + t) * H];
                nxt[12 + t] = wsQ[(k + 4 + t) * H];
            }
        }
#pragma unroll
        for (int n = 0; n < NB; ++n) {
            float4 z4 = *(const float4*)&za[n][k];
            aPf[n] = fmaf(z4.x, cur[0],  fmaf(z4.y, cur[1],  fmaf(z4.z, cur[2],  fmaf(z4.w, cur[3],  aPf[n]))));
            aQf[n] = fmaf(z4.x, cur[4],  fmaf(z4.y, cur[5],  fmaf(z4.z, cur[6],  fmaf(z4.w, cur[7],  aQf[n]))));
            aPs[n] = fmaf(z4.x, cur[8],  fmaf(z4.y, cur[9],  fmaf(z4.z, cur[10], fmaf(z4.w, cur[11], aPs[n]))));
            aQs[n] = fmaf(z4.x, cur[12], fmaf(z4.y, cur[13], fmaf(z4.z, cur[14], fmaf(z4.w, cur[15], aQs[n]))));
        }
#pragma unroll
        for (int t = 0; t < 16; ++t) cur[t] = nxt[t];
    }

#pragma unroll
    for (int n = 0; n < NB; ++n) {
        size_t o = (size_t)(n0 + n) * H + j;
        Pf[o] = aPf[n];
        Qf[o] = aQf[n];
        Ps[o] = aPs[n];
        Qs[o] = aQs[n];
    }
}

// Per edge: msgF = Pf[dst]+Qf[src]+ea.Wf[2H:2H+3]+bf ; msgS likewise;
// agg[dst] += sigmoid(msgF)*softplus(msgS).
__global__ __launch_bounds__(256) void edge_gather_kernel(const int* __restrict__ src,
                                                          const int* __restrict__ dst,
                                                          const float* __restrict__ ea,
                                                          const float* __restrict__ Wf,
                                                          const float* __restrict__ bf,
                                                          const float* __restrict__ Ws,
                                                          const float* __restrict__ bs,
                                                          const float* __restrict__ Pf,
                                                          const float* __restrict__ Qf,
                                                          const float* __restrict__ Ps,
                                                          const float* __restrict__ Qs,
                                                          float* __restrict__ agg) {
    int j = threadIdx.x & (H - 1);
    int half = threadIdx.x >> 7;
    float wf0 = Wf[256 * H + j], wf1 = Wf[257 * H + j], wf2 = Wf[258 * H + j];
    float ws0 = Ws[256 * H + j], ws1 = Ws[257 * H + j], ws2 = Ws[258 * H + j];
    float bfj = bf[j], bsj = bs[j];

    for (int e = blockIdx.x * 2 + half; e < NE; e += gridDim.x * 2) {
        int d = dst[e];
        int s = src[e];
        float e0 = ea[e * ED + 0], e1 = ea[e * ED + 1], e2 = ea[e * ED + 2];
        float f = Pf[(size_t)d * H + j] + Qf[(size_t)s * H + j];
        float v = Ps[(size_t)d * H + j] + Qs[(size_t)s * H + j];
        f = fmaf(e0, wf0, fmaf(e1, wf1, fmaf(e2, wf2, f + bfj)));
        v = fmaf(e0, ws0, fmaf(e1, ws1, fmaf(e2, ws2, v + bsj)));
        float sig = 1.0f / (1.0f + expf(-f));
        float sp  = fmaxf(v, 0.0f) + log1pf(expf(-fabsf(v)));
        atomicAdd(&agg[(size_t)d * H + j], sig * sp);
    }
}

// h += agg*invdeg; accumulate per-column sum and sum-of-squares in one pass.
__global__ __launch_bounds__(H) void resid_stats_kernel(float* __restrict__ h,
                                                        const float* __restrict__ agg,
                                                        const float* __restrict__ invdeg,
                                                        float* __restrict__ sum,
                                                        float* __restrict__ sumsq) {
    int j = threadIdx.x;
    float s = 0.0f, ss = 0.0f;
    for (int n = blockIdx.x; n < NN; n += gridDim.x) {
        float v = fmaf(agg[(size_t)n * H + j], invdeg[n], h[(size_t)n * H + j]);
        h[(size_t)n * H + j] = v;
        s += v;
        ss = fmaf(v, v, ss);
    }
    atomicAdd(&sum[j], s);
    atomicAdd(&sumsq[j], ss);
}

// Applies the last layer's BN+ReLU on the fly, pools into per-graph sums.
__global__ __launch_bounds__(H) void pool_kernel(const float* __restrict__ h,
                                                 const int* __restrict__ batch,
                                                 const float* __restrict__ sum,
                                                 const float* __restrict__ sumsq,
                                                 const float* __restrict__ gamma,
                                                 const float* __restrict__ beta,
                                                 float* __restrict__ g,
                                                 float* __restrict__ cnt) {
    int j = threadIdx.x;
    float mu  = sum[j] * (1.0f / NN);
    float var = sumsq[j] * (1.0f / NN) - mu * mu;
    float sc  = gamma[j] * rsqrtf(var + BN_EPSF);
    float sh  = beta[j] - mu * sc;
    for (int n = blockIdx.x; n < NN; n += gridDim.x) {
        int b = batch[n];
        float v = fmaf(h[(size_t)n * H + j], sc, sh);
        v = v > 0.0f ? v : 0.0f;
        atomicAdd(&g[(size_t)b * H + j], v);
        if (j == 0) atomicAdd(&cnt[b], 1.0f);
    }
}

__global__ __launch_bounds__(H) void mlp_kernel(const float* __restrict__ g,
                                                const float* __restrict__ cnt,
                                                const float* __restrict__ W1,
                                                const float* __restrict__ b1,
                                                const float* __restrict__ W2,
                                                const float* __restrict__ b2,
                                                const float* __restrict__ W3,
                                                const float* __restrict__ b3,
                                                float* __restrict__ out) {
    int gid = blockIdx.x, j = threadIdx.x;
    __shared__ float s1[H];
    __shared__ float s2[H];
    __shared__ float wsum[2];
    float c = cnt[gid];
    c = c < 1.0f ? 1.0f : c;
    s1[j] = g[gid * H + j] / c;
    __syncthreads();
    float a = b1[j];
    for (int k = 0; k < H; ++k) a = fmaf(s1[k], W1[k * H + j], a);
    a = a > 0.0f ? a : 0.0f;
    s2[j] = a;
    __syncthreads();
    float t = b2[j];
    for (int k = 0; k < H; ++k) t = fmaf(s2[k], W2[k * H + j], t);
    t = t > 0.0f ? t : 0.0f;
    float p = t * W3[j];
    for (int off = 32; off > 0; off >>= 1) p += __shfl_down(p, off, 64);
    if ((j & 63) == 0) wsum[j >> 6] = p;
    __syncthreads();
    if (j == 0) out[gid] = wsum[0] + wsum[1] + b3[0];
}

extern "C" void kernel_launch(void* const* d_in, const int* in_sizes, int n_in,
                              void* d_out, int out_size, void* d_ws, size_t ws_size,
                              hipStream_t stream) {
    const float* x     = (const float*)d_in[0];
    const int*   ei    = (const int*)d_in[1];
    const int*   srcp  = ei;        // edge_index[0] = source (x_j)
    const int*   dstp  = ei + NE;   // edge_index[1] = target (aggregation index)
    const int*   batch = (const int*)d_in[2];
    const float* ea    = (const float*)d_in[3];
    const float* Win   = (const float*)d_in[4];
    const float* bin   = (const float*)d_in[5];
    const float* Wf    = (const float*)d_in[6];
    const float* bf    = (const float*)d_in[7];
    const float* Ws    = (const float*)d_in[8];
    const float* bs    = (const float*)d_in[9];
    const float* gamma = (const float*)d_in[10];
    const float* beta  = (const float*)d_in[11];
    const float* W1    = (const float*)d_in[12];
    const float* b1    = (const float*)d_in[13];
    const float* W2    = (const float*)d_in[14];
    const float* b2    = (const float*)d_in[15];
    const float* W3    = (const float*)d_in[16];
    const float* b3    = (const float*)d_in[17];
    float* out = (float*)d_out;

    const size_t NH = (size_t)NN * H;
    float* ws    = (float*)d_ws;
    float* h     = ws;                 // NN*H
    float* agg   = h + NH;             // NN*H
    float* sum   = agg + NH;           // H   (zeroed together with agg)
    float* sumsq = sum + H;            // H
    float* degf  = sumsq + H;          // NN  (becomes invdeg)
    float* g     = degf + NN;          // NG*H
    float* cnt   = g + (size_t)NG * H; // NG
    float* Pf    = cnt + NG;           // NN*H
    float* Qf    = Pf + NH;            // NN*H
    float* Ps    = Qf + NH;            // NN*H
    float* Qs    = Ps + NH;            // NN*H

    hipMemsetAsync(degf, 0, NN * sizeof(float), stream);
    deg_kernel<<<(NE + 255) / 256, 256, 0, stream>>>(dstp, degf);
    invdeg_kernel<<<(NN + 255) / 256, 256, 0, stream>>>(degf);
    hin_kernel<<<NN, H, 0, stream>>>(x, Win, bin, h);

    const size_t ZDH = (size_t)(2 * H + ED) * H;   // per-layer weight stride
    for (int l = 0; l < NL; ++l) {
        const float* Wfl = Wf + (size_t)l * ZDH;
        const float* Wsl = Ws + (size_t)l * ZDH;
        // reads prev layer's sum/sumsq (before the memset below clears them)
        node_gemm_kernel<<<NN / NB, H, 0, stream>>>(h, Wfl, Wsl, sum, sumsq,
                                                    gamma + (size_t)(l ? l - 1 : 0) * H,
                                                    beta  + (size_t)(l ? l - 1 : 0) * H,
                                                    l > 0, Pf, Qf, Ps, Qs);
        hipMemsetAsync(agg, 0, (NH + 2 * H) * sizeof(float), stream);  // agg+sum+sumsq
        edge_gather_kernel<<<2000, 256, 0, stream>>>(srcp, dstp, ea,
                                                     Wfl, bf + (size_t)l * H,
                                                     Wsl, bs + (size_t)l * H,
                                                     Pf, Qf, Ps, Qs, agg);
        resid_stats_kernel<<<256, H, 0, stream>>>(h, agg, degf, sum, sumsq);
    }

    hipMemsetAsync(g, 0, ((size_t)NG * H + NG) * sizeof(float), stream);
    pool_kernel<<<2048, H, 0, stream>>>(h, batch, sum, sumsq,
                                        gamma + (size_t)(NL - 1) * H,
                                        beta + (size_t)(NL - 1) * H, g, cnt);
    mlp_kernel<<<NG, H, 0, stream>>>(g, cnt, W1, b1, W2, b2, W3, b3, out);
}

// Round 4
// 854.548 us; speedup vs baseline: 2.6774x; 1.2169x over previous
//
#include <hip/hip_runtime.h>
#include <math.h>

#define NN 20000
#define NE 160000
#define NG 1000
#define IND 11
#define H 128
#define ED 3
#define NL 5
#define NGB 32         /* nodes per block in node_gemm (two 16-row halves) */
#define BN_EPSF 1e-5f

// ---------------- CSR build (once per call) ----------------

__global__ void deg_int_kernel(const int* __restrict__ dst, int* __restrict__ degi) {
    int e = blockIdx.x * blockDim.x + threadIdx.x;
    if (e < NE) atomicAdd(&degi[dst[e]], 1);
}

// single-block exclusive scan over degi -> row_start/cursor; also invdeg.
__global__ __launch_bounds__(256) void scan_kernel(const int* __restrict__ degi,
                                                   int* __restrict__ row_start,
                                                   int* __restrict__ cursor,
                                                   float* __restrict__ invdeg) {
    __shared__ int wsum_s[4];
    __shared__ int s_off;
    int tid = threadIdx.x;
    int lane = tid & 63, wv = tid >> 6;
    if (tid == 0) s_off = 0;
    __syncthreads();
    for (int base = 0; base < NN; base += 256) {
        int i = base + tid;
        int v = (i < NN) ? degi[i] : 0;
        int x = v;
#pragma unroll
        for (int st = 1; st < 64; st <<= 1) {
            int y = __shfl_up(x, st, 64);
            if (lane >= st) x += y;
        }
        if (lane == 63) wsum_s[wv] = x;
        __syncthreads();
        int woff = 0;
        for (int w = 0; w < wv; ++w) woff += wsum_s[w];
        int total = wsum_s[0] + wsum_s[1] + wsum_s[2] + wsum_s[3];
        int off = s_off;
        if (i < NN) {
            int excl = off + woff + x - v;
            row_start[i] = excl;
            cursor[i] = excl;
            invdeg[i] = 1.0f / (float)(v < 1 ? 1 : v);
        }
        __syncthreads();
        if (tid == 0) s_off = off + total;
        __syncthreads();
    }
    if (tid == 0) row_start[NN] = NE;
}

// packs (ea0, ea1, ea2, src) per edge into dst-sorted order
__global__ void scatter_kernel(const int* __restrict__ src, const int* __restrict__ dst,
                               const float* __restrict__ ea,
                               int* __restrict__ cursor, float4* __restrict__ csr_ea4) {
    int e = blockIdx.x * blockDim.x + threadIdx.x;
    if (e < NE) {
        int d = dst[e];
        int pos = atomicAdd(&cursor[d], 1);
        float4 r;
        r.x = ea[e * ED + 0];
        r.y = ea[e * ED + 1];
        r.z = ea[e * ED + 2];
        r.w = __int_as_float(src[e]);
        csr_ea4[pos] = r;
    }
}

// ---------------- network ----------------

__global__ __launch_bounds__(H) void hin_kernel(const float* __restrict__ x,
                                                const float* __restrict__ Win,
                                                const float* __restrict__ bin,
                                                float* __restrict__ h) {
    int n = blockIdx.x;
    int j = threadIdx.x;
    __shared__ float xr[IND];
    if (j < IND) xr[j] = x[n * IND + j];
    __syncthreads();
    float acc = bin[j];
#pragma unroll
    for (int k = 0; k < IND; ++k) acc = fmaf(xr[k], Win[k * H + j], acc);
    h[n * H + j] = acc;
}

// Stages NGB rows of h (optionally applying previous layer's BN+ReLU in place),
// then computes interleaved node tables:
//   PD2[n][j] = (h@Wf[0:H], h@Ws[0:H])   (dst-side)
//   QS2[n][j] = (h@Wf[H:2H], h@Ws[H:2H]) (src-side)
// 256 threads: half = tid>>7 handles 16 rows; j = tid&127 is the column.
__global__ __launch_bounds__(256, 3) void node_gemm_kernel(float* __restrict__ h,
                                                           const float* __restrict__ Wf,
                                                           const float* __restrict__ Ws,
                                                           const float* __restrict__ sum,
                                                           const float* __restrict__ sumsq,
                                                           const float* __restrict__ gamma,
                                                           const float* __restrict__ beta,
                                                           int applyBN,
                                                           float* __restrict__ PD2,
                                                           float* __restrict__ QS2) {
    __shared__ __align__(16) float za[NGB][H];
    int j = threadIdx.x & (H - 1);
    int half = threadIdx.x >> 7;
    int r0 = half * 16;
    int n0 = blockIdx.x * NGB;

    if (applyBN) {
        float mu  = sum[j] * (1.0f / NN);
        float var = sumsq[j] * (1.0f / NN) - mu * mu;
        float sc  = gamma[j] * rsqrtf(var + BN_EPSF);
        float sh  = beta[j] - mu * sc;
#pragma unroll
        for (int n = 0; n < 16; ++n) {
            size_t o = (size_t)(n0 + r0 + n) * H + j;
            float v = fmaf(h[o], sc, sh);
            v = v > 0.0f ? v : 0.0f;
            h[o] = v;
            za[r0 + n][j] = v;
        }
    } else {
#pragma unroll
        for (int n = 0; n < 16; ++n) za[r0 + n][j] = h[(size_t)(n0 + r0 + n) * H + j];
    }
    __syncthreads();

    float aPf[16], aQf[16], aPs[16], aQs[16];
#pragma unroll
    for (int n = 0; n < 16; ++n) { aPf[n] = 0.f; aQf[n] = 0.f; aPs[n] = 0.f; aQs[n] = 0.f; }

    const float* wfP = Wf + j;           // Wf[k][j]
    const float* wfQ = Wf + H * H + j;   // Wf[H+k][j]
    const float* wsP = Ws + j;
    const float* wsQ = Ws + H * H + j;

    float cur[16], nxt[16];
#pragma unroll
    for (int t = 0; t < 4; ++t) {
        cur[t]      = wfP[t * H];
        cur[4 + t]  = wfQ[t * H];
        cur[8 + t]  = wsP[t * H];
        cur[12 + t] = wsQ[t * H];
    }

    for (int k = 0; k < H; k += 4) {
        if (k + 4 < H) {
#pragma unroll
            for (int t = 0; t < 4; ++t) {
                nxt[t]      = wfP[(k + 4 + t) * H];
                nxt[4 + t]  = wfQ[(k + 4 + t) * H];
                nxt[8 + t]  = wsP[(k + 4 + t) * H];
                nxt[12 + t] = wsQ[(k + 4 + t) * H];
            }
        }
#pragma unroll
        for (int n = 0; n < 16; ++n) {
            float4 z4 = *(const float4*)&za[r0 + n][k];
            aPf[n] = fmaf(z4.x, cur[0],  fmaf(z4.y, cur[1],  fmaf(z4.z, cur[2],  fmaf(z4.w, cur[3],  aPf[n]))));
            aQf[n] = fmaf(z4.x, cur[4],  fmaf(z4.y, cur[5],  fmaf(z4.z, cur[6],  fmaf(z4.w, cur[7],  aQf[n]))));
            aPs[n] = fmaf(z4.x, cur[8],  fmaf(z4.y, cur[9],  fmaf(z4.z, cur[10], fmaf(z4.w, cur[11], aPs[n]))));
            aQs[n] = fmaf(z4.x, cur[12], fmaf(z4.y, cur[13], fmaf(z4.z, cur[14], fmaf(z4.w, cur[15], aQs[n]))));
        }
#pragma unroll
        for (int t = 0; t < 16; ++t) cur[t] = nxt[t];
    }

#pragma unroll
    for (int n = 0; n < 16; ++n) {
        size_t o = (size_t)(n0 + r0 + n) * (2 * H) + 2 * j;
        *(float2*)&PD2[o] = make_float2(aPf[n], aPs[n]);
        *(float2*)&QS2[o] = make_float2(aQf[n], aQs[n]);
    }
}

// CSR aggregation fused with residual update + BN statistics.
// One block (128 threads) per node (grid-strided): reads PD2[d] once, loops
// incoming edges via LDS-staged (ea,src) float4, gathers QS2[src] as float2,
// accumulates messages in registers, then h[d] += acc*invdeg and local
// sum/sumsq accumulation (one atomic pair per thread at block end).
__global__ __launch_bounds__(128) void agg_fused_kernel(const int* __restrict__ row_start,
                                                        const float4* __restrict__ csr_ea4,
                                                        const float* __restrict__ Wf,
                                                        const float* __restrict__ bf,
                                                        const float* __restrict__ Ws,
                                                        const float* __restrict__ bs,
                                                        const float* __restrict__ PD2,
                                                        const float* __restrict__ QS2,
                                                        const float* __restrict__ invdeg,
                                                        float* __restrict__ h,
                                                        float* __restrict__ sum,
                                                        float* __restrict__ sumsq) {
    int j = threadIdx.x;
    float wf0 = Wf[256 * H + j], wf1 = Wf[257 * H + j], wf2 = Wf[258 * H + j];
    float ws0 = Ws[256 * H + j], ws1 = Ws[257 * H + j], ws2 = Ws[258 * H + j];
    float bfj = bf[j], bsj = bs[j];

    __shared__ __align__(16) float4 sfe[128];
    float ls = 0.0f, lss = 0.0f;

    for (int d = blockIdx.x; d < NN; d += gridDim.x) {
        int rs = row_start[d], re = row_start[d + 1];
        float2 pd = *(const float2*)&PD2[(size_t)d * (2 * H) + 2 * j];
        float fbase = pd.x + bfj;
        float sbase = pd.y + bsj;
        float acc = 0.0f;
        for (int base = rs; base < re; base += 128) {
            int cnt = re - base;
            cnt = cnt < 128 ? cnt : 128;
            __syncthreads();
            if (j < cnt) sfe[j] = csr_ea4[base + j];
            __syncthreads();
#pragma unroll 4
            for (int t = 0; t < cnt; ++t) {
                float4 fe = sfe[t];
                int s = __float_as_int(fe.w);
                float2 q = *(const float2*)&QS2[(size_t)s * (2 * H) + 2 * j];
                float f = fmaf(fe.x, wf0, fmaf(fe.y, wf1, fmaf(fe.z, wf2, fbase + q.x)));
                float v = fmaf(fe.x, ws0, fmaf(fe.y, ws1, fmaf(fe.z, ws2, sbase + q.y)));
                float sig = __builtin_amdgcn_rcpf(1.0f + __expf(-f));
                float sp  = fmaxf(v, 0.0f) + __logf(1.0f + __expf(-fabsf(v)));
                acc = fmaf(sig, sp, acc);
            }
        }
        float hv = fmaf(acc, invdeg[d], h[(size_t)d * H + j]);
        h[(size_t)d * H + j] = hv;
        ls += hv;
        lss = fmaf(hv, hv, lss);
    }
    atomicAdd(&sum[j], ls);
    atomicAdd(&sumsq[j], lss);
}

// Applies last layer's BN+ReLU on the fly, pools into per-graph sums.
__global__ __launch_bounds__(H) void pool_kernel(const float* __restrict__ h,
                                                 const int* __restrict__ batch,
                                                 const float* __restrict__ sum,
                                                 const float* __restrict__ sumsq,
                                                 const float* __restrict__ gamma,
                                                 const float* __restrict__ beta,
                                                 float* __restrict__ g,
                                                 float* __restrict__ cnt) {
    int j = threadIdx.x;
    float mu  = sum[j] * (1.0f / NN);
    float var = sumsq[j] * (1.0f / NN) - mu * mu;
    float sc  = gamma[j] * rsqrtf(var + BN_EPSF);
    float sh  = beta[j] - mu * sc;
    for (int n = blockIdx.x; n < NN; n += gridDim.x) {
        int b = batch[n];
        float v = fmaf(h[(size_t)n * H + j], sc, sh);
        v = v > 0.0f ? v : 0.0f;
        atomicAdd(&g[(size_t)b * H + j], v);
        if (j == 0) atomicAdd(&cnt[b], 1.0f);
    }
}

__global__ __launch_bounds__(H) void mlp_kernel(const float* __restrict__ g,
                                                const float* __restrict__ cnt,
                                                const float* __restrict__ W1,
                                                const float* __restrict__ b1,
                                                const float* __restrict__ W2,
                                                const float* __restrict__ b2,
                                                const float* __restrict__ W3,
                                                const float* __restrict__ b3,
                                                float* __restrict__ out) {
    int gid = blockIdx.x, j = threadIdx.x;
    __shared__ float s1[H];
    __shared__ float s2[H];
    __shared__ float wsum[2];
    float c = cnt[gid];
    c = c < 1.0f ? 1.0f : c;
    s1[j] = g[gid * H + j] / c;
    __syncthreads();
    float a = b1[j];
    for (int k = 0; k < H; ++k) a = fmaf(s1[k], W1[k * H + j], a);
    a = a > 0.0f ? a : 0.0f;
    s2[j] = a;
    __syncthreads();
    float t = b2[j];
    for (int k = 0; k < H; ++k) t = fmaf(s2[k], W2[k * H + j], t);
    t = t > 0.0f ? t : 0.0f;
    float p = t * W3[j];
    for (int off = 32; off > 0; off >>= 1) p += __shfl_down(p, off, 64);
    if ((j & 63) == 0) wsum[j >> 6] = p;
    __syncthreads();
    if (j == 0) out[gid] = wsum[0] + wsum[1] + b3[0];
}

extern "C" void kernel_launch(void* const* d_in, const int* in_sizes, int n_in,
                              void* d_out, int out_size, void* d_ws, size_t ws_size,
                              hipStream_t stream) {
    const float* x     = (const float*)d_in[0];
    const int*   ei    = (const int*)d_in[1];
    const int*   srcp  = ei;        // edge_index[0] = source (x_j)
    const int*   dstp  = ei + NE;   // edge_index[1] = target (aggregation index)
    const int*   batch = (const int*)d_in[2];
    const float* ea    = (const float*)d_in[3];
    const float* Win   = (const float*)d_in[4];
    const float* bin   = (const float*)d_in[5];
    const float* Wf    = (const float*)d_in[6];
    const float* bf    = (const float*)d_in[7];
    const float* Ws    = (const float*)d_in[8];
    const float* bs    = (const float*)d_in[9];
    const float* gamma = (const float*)d_in[10];
    const float* beta  = (const float*)d_in[11];
    const float* W1    = (const float*)d_in[12];
    const float* b1    = (const float*)d_in[13];
    const float* W2    = (const float*)d_in[14];
    const float* b2    = (const float*)d_in[15];
    const float* W3    = (const float*)d_in[16];
    const float* b3    = (const float*)d_in[17];
    float* out = (float*)d_out;

    const size_t NH = (size_t)NN * H;
    float* wsp   = (float*)d_ws;
    float* h     = wsp;                 // NN*H
    float* PD2   = h + NH;              // NN*2H
    float* QS2   = PD2 + 2 * NH;        // NN*2H
    float* invdeg= QS2 + 2 * NH;        // NN
    float* sum   = invdeg + NN;         // H
    float* sumsq = sum + H;             // H
    float* g     = sumsq + H;           // NG*H
    float* cnt   = g + (size_t)NG * H;  // NG  (1000 floats, keeps 16B alignment)
    float4* csr_ea4 = (float4*)(cnt + NG);       // NE float4
    int* degi      = (int*)(csr_ea4 + NE);       // NN
    int* row_start = degi + NN;                  // NN+1
    int* cursor    = row_start + NN + 1;         // NN

    // ---- CSR build (topology fixed across layers) ----
    hipMemsetAsync(degi, 0, NN * sizeof(int), stream);
    deg_int_kernel<<<(NE + 255) / 256, 256, 0, stream>>>(dstp, degi);
    scan_kernel<<<1, 256, 0, stream>>>(degi, row_start, cursor, invdeg);
    scatter_kernel<<<(NE + 255) / 256, 256, 0, stream>>>(srcp, dstp, ea, cursor, csr_ea4);

    hin_kernel<<<NN, H, 0, stream>>>(x, Win, bin, h);

    const size_t ZDH = (size_t)(2 * H + ED) * H;   // per-layer weight stride
    for (int l = 0; l < NL; ++l) {
        const float* Wfl = Wf + (size_t)l * ZDH;
        const float* Wsl = Ws + (size_t)l * ZDH;
        // reads previous layer's sum/sumsq (cleared only after this launch)
        node_gemm_kernel<<<NN / NGB, 256, 0, stream>>>(h, Wfl, Wsl, sum, sumsq,
                                                       gamma + (size_t)(l ? l - 1 : 0) * H,
                                                       beta  + (size_t)(l ? l - 1 : 0) * H,
                                                       l > 0, PD2, QS2);
        hipMemsetAsync(sum, 0, 2 * H * sizeof(float), stream);
        agg_fused_kernel<<<2048, H, 0, stream>>>(row_start, csr_ea4,
                                                 Wfl, bf + (size_t)l * H,
                                                 Wsl, bs + (size_t)l * H,
                                                 PD2, QS2, invdeg, h, sum, sumsq);
    }

    hipMemsetAsync(g, 0, ((size_t)NG * H + NG) * sizeof(float), stream);
    pool_kernel<<<2048, H, 0, stream>>>(h, batch, sum, sumsq,
                                        gamma + (size_t)(NL - 1) * H,
                                        beta + (size_t)(NL - 1) * H, g, cnt);
    mlp_kernel<<<NG, H, 0, stream>>>(g, cnt, W1, b1, W2, b2, W3, b3, out);
}